// Round 1
// baseline (1222.992 us; speedup 1.0000x reference)
//
#include <hip/hip_runtime.h>

typedef __attribute__((ext_vector_type(8))) short bf16x8;
typedef __attribute__((ext_vector_type(4))) float floatx4;

__device__ __forceinline__ unsigned short f2bf(float f) {
  unsigned int u = __builtin_bit_cast(unsigned int, f);
  unsigned int r = (u + 0x7fffu + ((u >> 16) & 1u)) >> 16;
  return (unsigned short)r;
}

__device__ __forceinline__ unsigned int pack2(float a, float b) {
  return (unsigned int)f2bf(a) | ((unsigned int)f2bf(b) << 16);
}

// C[row, col] = sum_k A[row,k] * B[col,k]  (both row-major, f32 in, bf16 out)
// Batched over z = b*H + h with per-operand (b,h) strides.
__global__ __launch_bounds__(256) void gemm_bt(
    const float* __restrict__ Abase, long sAb, long sAh,
    const float* __restrict__ Bbase, long sBb, long sBh,
    unsigned short* __restrict__ Cbase, long sC,
    int M, int Nc, int K, int H)
{
  int z = blockIdx.z;
  int b = z / H, h = z % H;
  const float* A  = Abase + (long)b * sAb + (long)h * sAh;
  const float* Bm = Bbase + (long)b * sBb + (long)h * sBh;
  unsigned short* C = Cbase + (long)z * sC;
  int tRow = blockIdx.x * 128;
  int tCol = blockIdx.y * 128;
  __shared__ __align__(16) unsigned short LA[128 * 72]; // [128][64] + pad 8 (stride 144B: 16B-aligned, 4-bank row shift)
  __shared__ __align__(16) unsigned short LB[128 * 72];
  int t = threadIdx.x;
  int l = t & 63, w = t >> 6;
  int wr = w >> 1, wc = w & 1;
  int l16 = l & 15, lq = l >> 4;
  floatx4 acc[4][4] = {};
  for (int k0 = 0; k0 < K; k0 += 64) {
    __syncthreads();
    for (int i = 0; i < 8; i++) {
      int lin = i * 256 + t;     // 2048 float4-chunks per 128x64 tile
      int row = lin >> 4;        // 16 chunks per row
      int c4  = lin & 15;
      float4 va = *reinterpret_cast<const float4*>(A + (long)(tRow + row) * K + k0 + c4 * 4);
      uint2 pa; pa.x = pack2(va.x, va.y); pa.y = pack2(va.z, va.w);
      *reinterpret_cast<uint2*>(&LA[row * 72 + c4 * 4]) = pa;
      float4 vb = *reinterpret_cast<const float4*>(Bm + (long)(tCol + row) * K + k0 + c4 * 4);
      uint2 pb; pb.x = pack2(vb.x, vb.y); pb.y = pack2(vb.z, vb.w);
      *reinterpret_cast<uint2*>(&LB[row * 72 + c4 * 4]) = pb;
    }
    __syncthreads();
    for (int kk = 0; kk < 2; kk++) {
      bf16x8 af[4], bfr[4];
      for (int m = 0; m < 4; m++)
        af[m]  = *reinterpret_cast<const bf16x8*>(&LA[(wr * 64 + m * 16 + l16) * 72 + kk * 32 + lq * 8]);
      for (int n = 0; n < 4; n++)
        bfr[n] = *reinterpret_cast<const bf16x8*>(&LB[(wc * 64 + n * 16 + l16) * 72 + kk * 32 + lq * 8]);
      for (int m = 0; m < 4; m++)
        for (int n = 0; n < 4; n++)
          acc[m][n] = __builtin_amdgcn_mfma_f32_16x16x32_bf16(af[m], bfr[n], acc[m][n], 0, 0, 0);
    }
  }
  for (int m = 0; m < 4; m++)
    for (int n = 0; n < 4; n++)
      for (int j = 0; j < 4; j++) {
        int row = tRow + wr * 64 + m * 16 + lq * 4 + j;
        int col = tCol + wc * 64 + n * 16 + l16;
        C[(long)row * Nc + col] = f2bf(acc[m][n][j]);
      }
}

// Fused causal relu-attention + head-sum + residual.
// Q,K: [b,h,2048,128] bf16;  Vt: [b,h,1024v,2048n] bf16;  x,out: [b,2048,1024] f32.
// Grid: x = v-block (8 x 128 wide), y = tile-pair (16), z = batch (2). 256 threads.
__global__ __launch_bounds__(256) void attn_fused(
    const unsigned short* __restrict__ Qb,
    const unsigned short* __restrict__ Kb,
    const unsigned short* __restrict__ Vtb,
    const float* __restrict__ x,
    float* __restrict__ out)
{
  const int b = blockIdx.z;
  const int pair = blockIdx.y;
  const int vb = blockIdx.x;
  const int t = threadIdx.x;
  const int l = t & 63, w = t >> 6;
  const int l16 = l & 15, lq = l >> 4;
  __shared__ __align__(16) unsigned short LK[64 * 136];  // [64 m][128 e] + pad
  __shared__ __align__(16) unsigned short LV[128 * 72];  // [128 v][64 m] + pad
  __shared__ __align__(16) unsigned short LP[64 * 72];   // [64 n][64 m] + pad
  const float inv_n = 1.0f / 2048.0f;

  for (int hf = 0; hf < 2; hf++) {
    const int T = hf ? (31 - pair) : pair;        // triangular pairing: T work + (31-T) work = const
    floatx4 acc[4][2] = {};                       // wave strip: 64 n x 32 v
    for (int h = 0; h < 8; h++) {
      const unsigned short* Qh = Qb + (((long)(b * 8 + h)) * 2048 + (long)T * 64) * 128;
      const unsigned short* Kh = Kb + ((long)(b * 8 + h)) * 2048 * 128;
      const unsigned short* Vh = Vtb + ((long)(b * 8 + h)) * 1024 * 2048 + (long)(vb * 128) * 2048;
      // Q fragments for this wave's S-strip (rows w*16 .. w*16+15), all 128 e
      bf16x8 aQ[4];
      for (int ke = 0; ke < 4; ke++)
        aQ[ke] = *reinterpret_cast<const bf16x8*>(Qh + (long)(w * 16 + l16) * 128 + ke * 32 + lq * 8);
      for (int M = 0; M <= T; M++) {
        __syncthreads();  // previous iteration's LK/LV/LP reads complete
        // stage K tile 64x128
        for (int i = 0; i < 4; i++) {
          int lin = i * 256 + t;
          int row = lin >> 4, c8 = lin & 15;
          *reinterpret_cast<uint4*>(&LK[row * 136 + c8 * 8]) =
              *reinterpret_cast<const uint4*>(Kh + (long)(M * 64 + row) * 128 + c8 * 8);
        }
        // stage Vt tile 128x64
        for (int i = 0; i < 4; i++) {
          int lin = i * 256 + t;
          int row = lin >> 3, c8 = lin & 7;
          *reinterpret_cast<uint4*>(&LV[row * 72 + c8 * 8]) =
              *reinterpret_cast<const uint4*>(Vh + (long)row * 2048 + M * 64 + c8 * 8);
        }
        __syncthreads();
        // S strip = Q(16x128) . K^T(128x64)
        floatx4 sacc[4] = {};
        for (int ke = 0; ke < 4; ke++)
          for (int mf = 0; mf < 4; mf++) {
            bf16x8 bK = *reinterpret_cast<const bf16x8*>(&LK[(mf * 16 + l16) * 136 + ke * 32 + lq * 8]);
            sacc[mf] = __builtin_amdgcn_mfma_f32_16x16x32_bf16(aQ[ke], bK, sacc[mf], 0, 0, 0);
          }
        // relu, causal mask (diag tile only), scale -> P (bf16 LDS)
        const int nloc = w * 16 + lq * 4;
        for (int mf = 0; mf < 4; mf++)
          for (int j = 0; j < 4; j++) {
            float v = fmaxf(sacc[mf][j], 0.0f) * inv_n;
            if (M == T) {
              int mm = mf * 16 + l16;
              if (mm > nloc + j) v = 0.0f;
            }
            LP[(nloc + j) * 72 + mf * 16 + l16] = f2bf(v);
          }
        __syncthreads();
        // acc += P(64x64) . V(64 x 32-slice)
        for (int km = 0; km < 2; km++) {
          bf16x8 aP[4];
          for (int nf = 0; nf < 4; nf++)
            aP[nf] = *reinterpret_cast<const bf16x8*>(&LP[(nf * 16 + l16) * 72 + km * 32 + lq * 8]);
          for (int vf = 0; vf < 2; vf++) {
            bf16x8 bV = *reinterpret_cast<const bf16x8*>(&LV[(w * 32 + vf * 16 + l16) * 72 + km * 32 + lq * 8]);
            for (int nf = 0; nf < 4; nf++)
              acc[nf][vf] = __builtin_amdgcn_mfma_f32_16x16x32_bf16(aP[nf], bV, acc[nf][vf], 0, 0, 0);
          }
        }
      }  // M
    }  // h
    // epilogue: residual add, f32 out
    for (int nf = 0; nf < 4; nf++)
      for (int vf = 0; vf < 2; vf++)
        for (int j = 0; j < 4; j++) {
          int n = T * 64 + nf * 16 + lq * 4 + j;
          int v = vb * 128 + w * 32 + vf * 16 + l16;
          long idx = ((long)b * 2048 + n) * 1024 + v;
          out[idx] = x[idx] + acc[nf][vf][j];
        }
  }  // hf
}

extern "C" void kernel_launch(void* const* d_in, const int* in_sizes, int n_in,
                              void* d_out, int out_size, void* d_ws, size_t ws_size,
                              hipStream_t stream) {
  const float* x  = (const float*)d_in[0];
  const float* Wq = (const float*)d_in[1];
  const float* Wk = (const float*)d_in[2];
  const float* Wv = (const float*)d_in[3];
  float* out = (float*)d_out;

  // workspace: Q 8MB | K 8MB | Vt 64MB (bf16)
  unsigned short* Qb  = (unsigned short*)d_ws;
  unsigned short* Kb  = Qb + (size_t)2 * 8 * 2048 * 128;
  unsigned short* Vtb = Kb + (size_t)2 * 8 * 2048 * 128;

  dim3 blk(256);
  // Q[z][n,e] = x[b] (2048x1024) . Wq[h]^T   (M=2048, Nc=128, K=1024)
  gemm_bt<<<dim3(16, 1, 16), blk, 0, stream>>>(
      x, (long)2048 * 1024, 0, Wq, 0, (long)128 * 1024,
      Qb, (long)2048 * 128, 2048, 128, 1024, 8);
  // K
  gemm_bt<<<dim3(16, 1, 16), blk, 0, stream>>>(
      x, (long)2048 * 1024, 0, Wk, 0, (long)128 * 1024,
      Kb, (long)2048 * 128, 2048, 128, 1024, 8);
  // Vt[z][v,n] = Wv[h] (1024x1024) . x[b]^T  (M=1024, Nc=2048, K=1024) -> V transposed
  gemm_bt<<<dim3(8, 16, 16), blk, 0, stream>>>(
      Wv, 0, (long)1024 * 1024, x, (long)2048 * 1024, 0,
      Vtb, (long)1024 * 2048, 1024, 2048, 1024, 8);
  // fused attention
  attn_fused<<<dim3(8, 16, 2), blk, 0, stream>>>(Qb, Kb, Vtb, x, out);
}

// Round 2
// 584.377 us; speedup vs baseline: 2.0928x; 2.0928x over previous
//
#include <hip/hip_runtime.h>

typedef __attribute__((ext_vector_type(8))) short bf16x8;
typedef __attribute__((ext_vector_type(4))) float floatx4;

__device__ __forceinline__ unsigned short f2bf(float f) {
  unsigned int u = __builtin_bit_cast(unsigned int, f);
  unsigned int r = (u + 0x7fffu + ((u >> 16) & 1u)) >> 16;
  return (unsigned short)r;
}

__device__ __forceinline__ unsigned int pack2(float a, float b) {
  return (unsigned int)f2bf(a) | ((unsigned int)f2bf(b) << 16);
}

// out = x (residual init; attn accumulates with atomics on top)
__global__ __launch_bounds__(256) void init_out(const float4* __restrict__ x,
                                                float4* __restrict__ out, int n4) {
  for (int i = blockIdx.x * 256 + threadIdx.x; i < n4; i += gridDim.x * 256)
    out[i] = x[i];
}

// C[row, col] = sum_k A[row,k] * B[col,k]  (both row-major, f32 in, bf16 out)
// Batched over z = b*H + h with per-operand (b,h) strides.
__global__ __launch_bounds__(256) void gemm_bt(
    const float* __restrict__ Abase, long sAb, long sAh,
    const float* __restrict__ Bbase, long sBb, long sBh,
    unsigned short* __restrict__ Cbase, long sC,
    int M, int Nc, int K, int H)
{
  int z = blockIdx.z;
  int b = z / H, h = z % H;
  const float* A  = Abase + (long)b * sAb + (long)h * sAh;
  const float* Bm = Bbase + (long)b * sBb + (long)h * sBh;
  unsigned short* C = Cbase + (long)z * sC;
  int tRow = blockIdx.x * 128;
  int tCol = blockIdx.y * 128;
  __shared__ __align__(16) unsigned short LA[128 * 72];
  __shared__ __align__(16) unsigned short LB[128 * 72];
  int t = threadIdx.x;
  int l = t & 63, w = t >> 6;
  int wr = w >> 1, wc = w & 1;
  int l16 = l & 15, lq = l >> 4;
  floatx4 acc[4][4] = {};
  for (int k0 = 0; k0 < K; k0 += 64) {
    __syncthreads();
    for (int i = 0; i < 8; i++) {
      int lin = i * 256 + t;
      int row = lin >> 4;
      int c4  = lin & 15;
      float4 va = *reinterpret_cast<const float4*>(A + (long)(tRow + row) * K + k0 + c4 * 4);
      uint2 pa; pa.x = pack2(va.x, va.y); pa.y = pack2(va.z, va.w);
      *reinterpret_cast<uint2*>(&LA[row * 72 + c4 * 4]) = pa;
      float4 vb = *reinterpret_cast<const float4*>(Bm + (long)(tCol + row) * K + k0 + c4 * 4);
      uint2 pb; pb.x = pack2(vb.x, vb.y); pb.y = pack2(vb.z, vb.w);
      *reinterpret_cast<uint2*>(&LB[row * 72 + c4 * 4]) = pb;
    }
    __syncthreads();
    for (int kk = 0; kk < 2; kk++) {
      bf16x8 af[4], bfr[4];
      for (int m = 0; m < 4; m++)
        af[m]  = *reinterpret_cast<const bf16x8*>(&LA[(wr * 64 + m * 16 + l16) * 72 + kk * 32 + lq * 8]);
      for (int n = 0; n < 4; n++)
        bfr[n] = *reinterpret_cast<const bf16x8*>(&LB[(wc * 64 + n * 16 + l16) * 72 + kk * 32 + lq * 8]);
      for (int m = 0; m < 4; m++)
        for (int n = 0; n < 4; n++)
          acc[m][n] = __builtin_amdgcn_mfma_f32_16x16x32_bf16(af[m], bfr[n], acc[m][n], 0, 0, 0);
    }
  }
  for (int m = 0; m < 4; m++)
    for (int n = 0; n < 4; n++)
      for (int j = 0; j < 4; j++) {
        int row = tRow + wr * 64 + m * 16 + lq * 4 + j;
        int col = tCol + wc * 64 + n * 16 + l16;
        C[(long)row * Nc + col] = f2bf(acc[m][n][j]);
      }
}

// Q and K projections in one launch: blockIdx.y selects (Wq->Qb) or (Wk->Kb).
__global__ __launch_bounds__(256) void gemm_qk(
    const float* __restrict__ x,
    const float* __restrict__ Wq, const float* __restrict__ Wk,
    unsigned short* __restrict__ Qb, unsigned short* __restrict__ Kb)
{
  int z = blockIdx.z;
  int b = z >> 3, h = z & 7;
  const float* A  = x + (long)b * 2048 * 1024;
  const float* Bm = (blockIdx.y ? Wk : Wq) + (long)h * 128 * 1024;
  unsigned short* C = (blockIdx.y ? Kb : Qb) + (long)z * 2048 * 128;
  int tRow = blockIdx.x * 128;
  __shared__ __align__(16) unsigned short LA[128 * 72];
  __shared__ __align__(16) unsigned short LB[128 * 72];
  int t = threadIdx.x;
  int l = t & 63, w = t >> 6;
  int wr = w >> 1, wc = w & 1;
  int l16 = l & 15, lq = l >> 4;
  floatx4 acc[4][4] = {};
  const int K = 1024;
  for (int k0 = 0; k0 < K; k0 += 64) {
    __syncthreads();
    for (int i = 0; i < 8; i++) {
      int lin = i * 256 + t;
      int row = lin >> 4;
      int c4  = lin & 15;
      float4 va = *reinterpret_cast<const float4*>(A + (long)(tRow + row) * K + k0 + c4 * 4);
      uint2 pa; pa.x = pack2(va.x, va.y); pa.y = pack2(va.z, va.w);
      *reinterpret_cast<uint2*>(&LA[row * 72 + c4 * 4]) = pa;
      if (row < 128) {  // B tile is 128x64 but only 128 rows exist (Nc=128): rows>=128 map mod
        int brow = row;
        const float* bp = Bm + (long)brow * K + k0 + c4 * 4;
        float4 vb = (brow < 128) ? *reinterpret_cast<const float4*>(bp) : float4{0,0,0,0};
        uint2 pb; pb.x = pack2(vb.x, vb.y); pb.y = pack2(vb.z, vb.w);
        *reinterpret_cast<uint2*>(&LB[row * 72 + c4 * 4]) = pb;
      }
    }
    __syncthreads();
    for (int kk = 0; kk < 2; kk++) {
      bf16x8 af[4], bfr[4];
      for (int m = 0; m < 4; m++)
        af[m]  = *reinterpret_cast<const bf16x8*>(&LA[(wr * 64 + m * 16 + l16) * 72 + kk * 32 + lq * 8]);
      for (int n = 0; n < 4; n++)
        bfr[n] = *reinterpret_cast<const bf16x8*>(&LB[(wc * 64 + n * 16 + l16) * 72 + kk * 32 + lq * 8]);
      for (int m = 0; m < 4; m++)
        for (int n = 0; n < 4; n++)
          acc[m][n] = __builtin_amdgcn_mfma_f32_16x16x32_bf16(af[m], bfr[n], acc[m][n], 0, 0, 0);
    }
  }
  // Nc=128: only wc covering cols 0..127 -> col = wc*64 + n*16 + l16 < 128 always true
  for (int m = 0; m < 4; m++)
    for (int n = 0; n < 4; n++)
      for (int j = 0; j < 4; j++) {
        int row = tRow + wr * 64 + m * 16 + lq * 4 + j;
        int col = wc * 64 + n * 16 + l16;
        C[(long)row * 128 + col] = f2bf(acc[m][n][j]);
      }
}

// Fused causal relu-attention, one head per WG, atomic head-sum into out.
// Q,K: [b,h,2048,128] bf16;  Vt: [b,h,1024v,2048n] bf16;  out: [b,2048,1024] f32 (pre-init = x).
// Grid: x = v-block (8 x 128 wide), y = tile-pair (16), z = b*8+h (16). 256 threads.
__global__ __launch_bounds__(256) void attn_fused(
    const unsigned short* __restrict__ Qb,
    const unsigned short* __restrict__ Kb,
    const unsigned short* __restrict__ Vtb,
    float* __restrict__ out)
{
  const int z = blockIdx.z;
  const int b = z >> 3;
  const int pair = blockIdx.y;
  const int vb = blockIdx.x;
  const int t = threadIdx.x;
  const int l = t & 63, w = t >> 6;
  const int l16 = l & 15, lq = l >> 4;
  __shared__ __align__(16) unsigned short LK[64 * 136];  // [64 m][128 e] + pad; P aliases here
  __shared__ __align__(16) unsigned short LV[128 * 72];  // [128 v][64 m] + pad
  unsigned short* LP = LK;                                // alias: P written after K reads done
  const float inv_n = 1.0f / 2048.0f;
  const unsigned short* Qz = Qb + (long)z * 2048 * 128;
  const unsigned short* Kh = Kb + (long)z * 2048 * 128;
  const unsigned short* Vh = Vtb + (long)z * 1024 * 2048 + (long)(vb * 128) * 2048;

  for (int hf = 0; hf < 2; hf++) {
    const int T = hf ? (31 - pair) : pair;  // triangular pairing: constant work per WG
    floatx4 acc[4][2] = {};                 // wave strip: 64 n x 32 v
    const unsigned short* Qh = Qz + (long)T * 64 * 128;
    bf16x8 aQ[4];
    for (int ke = 0; ke < 4; ke++)
      aQ[ke] = *reinterpret_cast<const bf16x8*>(Qh + (long)(w * 16 + l16) * 128 + ke * 32 + lq * 8);
    for (int M = 0; M <= T; M++) {
      __syncthreads();  // previous iteration's LP/LV reads complete
      // stage K tile 64x128
      for (int i = 0; i < 4; i++) {
        int lin = i * 256 + t;
        int row = lin >> 4, c8 = lin & 15;
        *reinterpret_cast<uint4*>(&LK[row * 136 + c8 * 8]) =
            *reinterpret_cast<const uint4*>(Kh + (long)(M * 64 + row) * 128 + c8 * 8);
      }
      // stage Vt tile 128x64
      for (int i = 0; i < 4; i++) {
        int lin = i * 256 + t;
        int row = lin >> 3, c8 = lin & 7;
        *reinterpret_cast<uint4*>(&LV[row * 72 + c8 * 8]) =
            *reinterpret_cast<const uint4*>(Vh + (long)row * 2048 + M * 64 + c8 * 8);
      }
      __syncthreads();
      // S strip = Q(16x128) . K^T(128x64)
      floatx4 sacc[4] = {};
      for (int ke = 0; ke < 4; ke++)
        for (int mf = 0; mf < 4; mf++) {
          bf16x8 bK = *reinterpret_cast<const bf16x8*>(&LK[(mf * 16 + l16) * 136 + ke * 32 + lq * 8]);
          sacc[mf] = __builtin_amdgcn_mfma_f32_16x16x32_bf16(aQ[ke], bK, sacc[mf], 0, 0, 0);
        }
      __syncthreads();  // all K reads done before P overwrites LK region
      // relu, causal mask (diag tile only), scale -> P (bf16, aliased LDS)
      const int nloc = w * 16 + lq * 4;
      for (int mf = 0; mf < 4; mf++)
        for (int j = 0; j < 4; j++) {
          float v = fmaxf(sacc[mf][j], 0.0f) * inv_n;
          if (M == T) {
            int mm = mf * 16 + l16;
            if (mm > nloc + j) v = 0.0f;
          }
          LP[(nloc + j) * 72 + mf * 16 + l16] = f2bf(v);
        }
      __syncthreads();
      // acc += P(64x64) . V(64 x 32-slice)
      for (int km = 0; km < 2; km++) {
        bf16x8 aP[4];
        for (int nf = 0; nf < 4; nf++)
          aP[nf] = *reinterpret_cast<const bf16x8*>(&LP[(nf * 16 + l16) * 72 + km * 32 + lq * 8]);
        for (int vf = 0; vf < 2; vf++) {
          bf16x8 bV = *reinterpret_cast<const bf16x8*>(&LV[(w * 32 + vf * 16 + l16) * 72 + km * 32 + lq * 8]);
          for (int nf = 0; nf < 4; nf++)
            acc[nf][vf] = __builtin_amdgcn_mfma_f32_16x16x32_bf16(aP[nf], bV, acc[nf][vf], 0, 0, 0);
        }
      }
    }  // M
    // epilogue: atomic head-sum into out (pre-initialized to x)
    for (int nf = 0; nf < 4; nf++)
      for (int vf = 0; vf < 2; vf++)
        for (int j = 0; j < 4; j++) {
          int n = T * 64 + nf * 16 + lq * 4 + j;
          int v = vb * 128 + w * 32 + vf * 16 + l16;
          long idx = ((long)b * 2048 + n) * 1024 + v;
          unsafeAtomicAdd(&out[idx], acc[nf][vf][j]);
        }
  }  // hf
}

extern "C" void kernel_launch(void* const* d_in, const int* in_sizes, int n_in,
                              void* d_out, int out_size, void* d_ws, size_t ws_size,
                              hipStream_t stream) {
  const float* x  = (const float*)d_in[0];
  const float* Wq = (const float*)d_in[1];
  const float* Wk = (const float*)d_in[2];
  const float* Wv = (const float*)d_in[3];
  float* out = (float*)d_out;

  unsigned short* Qb  = (unsigned short*)d_ws;
  unsigned short* Kb  = Qb + (size_t)2 * 8 * 2048 * 128;
  unsigned short* Vtb = Kb + (size_t)2 * 8 * 2048 * 128;

  dim3 blk(256);
  // out = x
  init_out<<<dim3(1024), blk, 0, stream>>>(
      (const float4*)x, (float4*)out, 2 * 2048 * 1024 / 4);
  // Q and K projections (one launch, y selects which)
  gemm_qk<<<dim3(16, 2, 16), blk, 0, stream>>>(x, Wq, Wk, Qb, Kb);
  // Vt[z][v,n] = Wv[h] (1024x1024) . x[b]^T
  gemm_bt<<<dim3(8, 16, 16), blk, 0, stream>>>(
      Wv, 0, (long)1024 * 1024, x, (long)2048 * 1024, 0,
      Vtb, (long)1024 * 2048, 1024, 2048, 1024, 8);
  // fused attention, one head per WG, atomic accumulate
  attn_fused<<<dim3(8, 16, 16), blk, 0, stream>>>(Qb, Kb, Vtb, out);
}

// Round 3
// 389.666 us; speedup vs baseline: 3.1386x; 1.4997x over previous
//
#include <hip/hip_runtime.h>

typedef __attribute__((ext_vector_type(8))) short bf16x8;
typedef __attribute__((ext_vector_type(4))) float floatx4;

__device__ __forceinline__ unsigned short f2bf(float f) {
  unsigned int u = __builtin_bit_cast(unsigned int, f);
  unsigned int r = (u + 0x7fffu + ((u >> 16) & 1u)) >> 16;
  return (unsigned short)r;
}

__device__ __forceinline__ unsigned int pack2(float a, float b) {
  return (unsigned int)f2bf(a) | ((unsigned int)f2bf(b) << 16);
}

__device__ __forceinline__ void gload16(const void* g, void* l) {
  __builtin_amdgcn_global_load_lds(
      (__attribute__((address_space(1))) void*)g,
      (__attribute__((address_space(3))) void*)l, 16, 0, 0);
}

// out = x (residual init; attn accumulates with atomics on top)
__global__ __launch_bounds__(256) void init_out(const float4* __restrict__ x,
                                                float4* __restrict__ out, int n4) {
  for (int i = blockIdx.x * 256 + threadIdx.x; i < n4; i += gridDim.x * 256)
    out[i] = x[i];
}

// f32 -> bf16 for x, [Wq;Wk] concat (per head: 256 rows), Wv.
__global__ __launch_bounds__(256) void convert_all(
    const float4* __restrict__ x4,
    const float4* __restrict__ wq4, const float4* __restrict__ wk4,
    const float4* __restrict__ wv4,
    uint2* __restrict__ xb4, uint2* __restrict__ wqkb4, uint2* __restrict__ wvb4)
{
  const int NX = 2 * 2048 * 1024 / 4;   // 1048576
  const int NQK = 8 * 256 * 1024 / 4;   // 524288
  const int NV = 8 * 1024 * 1024 / 4;   // 2097152
  const int total = NX + NQK + NV;
  for (int i = blockIdx.x * 256 + threadIdx.x; i < total; i += gridDim.x * 256) {
    float4 f; uint2* dst;
    if (i < NX) {
      f = x4[i]; dst = &xb4[i];
    } else if (i < NX + NQK) {
      int j = i - NX;
      int c = j & 255;            // 256 float4-chunks per 1024-row
      int row = j >> 8;           // h*256 + r
      int h = row >> 8, r = row & 255;
      f = (r < 128) ? wq4[(h * 128 + r) * 256 + c] : wk4[(h * 128 + r - 128) * 256 + c];
      dst = &wqkb4[j];
    } else {
      int j = i - NX - NQK;
      f = wv4[j]; dst = &wvb4[j];
    }
    uint2 p; p.x = pack2(f.x, f.y); p.y = pack2(f.z, f.w);
    *dst = p;
  }
}

// bf16 B^T GEMM, m97 structure: 128x128 tile, BK=64, linear LDS, global_load_lds.
// C[row,col] = sum_k A[row,k]*B[col,k]; col<split -> C0, else C1 (col-split).
__global__ __launch_bounds__(256) void gemm_bf16_bt(
    const unsigned short* __restrict__ Abase, long sAb, long sAh,
    const unsigned short* __restrict__ Bbase, long sBb, long sBh,
    unsigned short* __restrict__ C0base, long sC0, int ld0,
    unsigned short* __restrict__ C1base, long sC1, int ld1,
    int split, int K)
{
  const int z = blockIdx.z;
  const int b = z >> 3, h = z & 7;
  const unsigned short* Ag = Abase + (long)b * sAb + (long)h * sAh + (long)blockIdx.x * 128 * K;
  const unsigned short* Bg = Bbase + (long)b * sBb + (long)h * sBh + (long)blockIdx.y * 128 * K;
  __shared__ __align__(16) unsigned short LA[128 * 64];  // linear (global_load_lds constraint)
  __shared__ __align__(16) unsigned short LB[128 * 64];
  const int t = threadIdx.x;
  const int l = t & 63, w = t >> 6;
  const int wr = w >> 1, wc = w & 1;
  const int l16 = l & 15, lq = l >> 4;
  floatx4 acc[4][4] = {};
  for (int k0 = 0; k0 < K; k0 += 64) {
    __syncthreads();  // prev tile's ds_reads complete before overwrite
    for (int i = 0; i < 4; i++) {
      int cbase = i * 256 + (t & 192);      // wave-uniform chunk base
      int chunk = cbase + (t & 63);         // this lane's 16B chunk
      int row = chunk >> 3, c8 = chunk & 7;
      gload16(Ag + (long)row * K + k0 + c8 * 8, &LA[cbase * 8]);
      gload16(Bg + (long)row * K + k0 + c8 * 8, &LB[cbase * 8]);
    }
    __syncthreads();  // compiler drains vmcnt before barrier
    for (int kk = 0; kk < 2; kk++) {
      bf16x8 af[4], bfr[4];
      for (int m = 0; m < 4; m++)
        af[m]  = *reinterpret_cast<const bf16x8*>(&LA[(wr * 64 + m * 16 + l16) * 64 + kk * 32 + lq * 8]);
      for (int n = 0; n < 4; n++)
        bfr[n] = *reinterpret_cast<const bf16x8*>(&LB[(wc * 64 + n * 16 + l16) * 64 + kk * 32 + lq * 8]);
      for (int m = 0; m < 4; m++)
        for (int n = 0; n < 4; n++)
          acc[m][n] = __builtin_amdgcn_mfma_f32_16x16x32_bf16(af[m], bfr[n], acc[m][n], 0, 0, 0);
    }
  }
  unsigned short* C0 = C0base + (long)z * sC0;
  unsigned short* C1 = C1base + (long)z * sC1;
  for (int m = 0; m < 4; m++)
    for (int n = 0; n < 4; n++)
      for (int j = 0; j < 4; j++) {
        int row = blockIdx.x * 128 + wr * 64 + m * 16 + lq * 4 + j;
        int col = blockIdx.y * 128 + wc * 64 + n * 16 + l16;
        unsigned short v = f2bf(acc[m][n][j]);
        if (col < split) C0[(long)row * ld0 + col] = v;
        else             C1[(long)row * ld1 + (col - split)] = v;
      }
}

// ---------------- fallback (f32-staging) path, used if ws too small ----------
__global__ __launch_bounds__(256) void gemm_bt(
    const float* __restrict__ Abase, long sAb, long sAh,
    const float* __restrict__ Bbase, long sBb, long sBh,
    unsigned short* __restrict__ Cbase, long sC,
    int M, int Nc, int K, int H)
{
  int z = blockIdx.z;
  int b = z / H, h = z % H;
  const float* A  = Abase + (long)b * sAb + (long)h * sAh;
  const float* Bm = Bbase + (long)b * sBb + (long)h * sBh;
  unsigned short* C = Cbase + (long)z * sC;
  int tRow = blockIdx.x * 128;
  int tCol = blockIdx.y * 128;
  __shared__ __align__(16) unsigned short LA[128 * 72];
  __shared__ __align__(16) unsigned short LB[128 * 72];
  int t = threadIdx.x;
  int l = t & 63, w = t >> 6;
  int wr = w >> 1, wc = w & 1;
  int l16 = l & 15, lq = l >> 4;
  floatx4 acc[4][4] = {};
  for (int k0 = 0; k0 < K; k0 += 64) {
    __syncthreads();
    for (int i = 0; i < 8; i++) {
      int lin = i * 256 + t;
      int row = lin >> 4;
      int c4  = lin & 15;
      float4 va = *reinterpret_cast<const float4*>(A + (long)(tRow + row) * K + k0 + c4 * 4);
      uint2 pa; pa.x = pack2(va.x, va.y); pa.y = pack2(va.z, va.w);
      *reinterpret_cast<uint2*>(&LA[row * 72 + c4 * 4]) = pa;
      float4 vb = *reinterpret_cast<const float4*>(Bm + (long)(tCol + row) * K + k0 + c4 * 4);
      uint2 pb; pb.x = pack2(vb.x, vb.y); pb.y = pack2(vb.z, vb.w);
      *reinterpret_cast<uint2*>(&LB[row * 72 + c4 * 4]) = pb;
    }
    __syncthreads();
    for (int kk = 0; kk < 2; kk++) {
      bf16x8 af[4], bfr[4];
      for (int m = 0; m < 4; m++)
        af[m]  = *reinterpret_cast<const bf16x8*>(&LA[(wr * 64 + m * 16 + l16) * 72 + kk * 32 + lq * 8]);
      for (int n = 0; n < 4; n++)
        bfr[n] = *reinterpret_cast<const bf16x8*>(&LB[(wc * 64 + n * 16 + l16) * 72 + kk * 32 + lq * 8]);
      for (int m = 0; m < 4; m++)
        for (int n = 0; n < 4; n++)
          acc[m][n] = __builtin_amdgcn_mfma_f32_16x16x32_bf16(af[m], bfr[n], acc[m][n], 0, 0, 0);
    }
  }
  for (int m = 0; m < 4; m++)
    for (int n = 0; n < 4; n++)
      for (int j = 0; j < 4; j++) {
        int row = tRow + wr * 64 + m * 16 + lq * 4 + j;
        int col = tCol + wc * 64 + n * 16 + l16;
        C[(long)row * Nc + col] = f2bf(acc[m][n][j]);
      }
}

__global__ __launch_bounds__(256) void gemm_qk(
    const float* __restrict__ x,
    const float* __restrict__ Wq, const float* __restrict__ Wk,
    unsigned short* __restrict__ Qb, unsigned short* __restrict__ Kb)
{
  int z = blockIdx.z;
  int b = z >> 3, h = z & 7;
  const float* A  = x + (long)b * 2048 * 1024;
  const float* Bm = (blockIdx.y ? Wk : Wq) + (long)h * 128 * 1024;
  unsigned short* C = (blockIdx.y ? Kb : Qb) + (long)z * 2048 * 128;
  int tRow = blockIdx.x * 128;
  __shared__ __align__(16) unsigned short LA[128 * 72];
  __shared__ __align__(16) unsigned short LB[128 * 72];
  int t = threadIdx.x;
  int l = t & 63, w = t >> 6;
  int wr = w >> 1, wc = w & 1;
  int l16 = l & 15, lq = l >> 4;
  floatx4 acc[4][4] = {};
  const int K = 1024;
  for (int k0 = 0; k0 < K; k0 += 64) {
    __syncthreads();
    for (int i = 0; i < 8; i++) {
      int lin = i * 256 + t;
      int row = lin >> 4;
      int c4  = lin & 15;
      float4 va = *reinterpret_cast<const float4*>(A + (long)(tRow + row) * K + k0 + c4 * 4);
      uint2 pa; pa.x = pack2(va.x, va.y); pa.y = pack2(va.z, va.w);
      *reinterpret_cast<uint2*>(&LA[row * 72 + c4 * 4]) = pa;
      float4 vb = *reinterpret_cast<const float4*>(Bm + (long)row * K + k0 + c4 * 4);
      uint2 pb; pb.x = pack2(vb.x, vb.y); pb.y = pack2(vb.z, vb.w);
      *reinterpret_cast<uint2*>(&LB[row * 72 + c4 * 4]) = pb;
    }
    __syncthreads();
    for (int kk = 0; kk < 2; kk++) {
      bf16x8 af[4], bfr[4];
      for (int m = 0; m < 4; m++)
        af[m]  = *reinterpret_cast<const bf16x8*>(&LA[(wr * 64 + m * 16 + l16) * 72 + kk * 32 + lq * 8]);
      for (int n = 0; n < 4; n++)
        bfr[n] = *reinterpret_cast<const bf16x8*>(&LB[(wc * 64 + n * 16 + l16) * 72 + kk * 32 + lq * 8]);
      for (int m = 0; m < 4; m++)
        for (int n = 0; n < 4; n++)
          acc[m][n] = __builtin_amdgcn_mfma_f32_16x16x32_bf16(af[m], bfr[n], acc[m][n], 0, 0, 0);
    }
  }
  for (int m = 0; m < 4; m++)
    for (int n = 0; n < 4; n++)
      for (int j = 0; j < 4; j++) {
        int row = tRow + wr * 64 + m * 16 + lq * 4 + j;
        int col = wc * 64 + n * 16 + l16;
        C[(long)row * 128 + col] = f2bf(acc[m][n][j]);
      }
}
// ---------------------------------------------------------------------------

// Fused causal relu-attention, one head per WG, atomic head-sum into out.
__global__ __launch_bounds__(256) void attn_fused(
    const unsigned short* __restrict__ Qb,
    const unsigned short* __restrict__ Kb,
    const unsigned short* __restrict__ Vtb,
    float* __restrict__ out)
{
  const int z = blockIdx.z;
  const int b = z >> 3;
  const int pair = blockIdx.y;
  const int vb = blockIdx.x;
  const int t = threadIdx.x;
  const int l = t & 63, w = t >> 6;
  const int l16 = l & 15, lq = l >> 4;
  __shared__ __align__(16) unsigned short LK[64 * 136];  // P aliases here
  __shared__ __align__(16) unsigned short LV[128 * 72];
  unsigned short* LP = LK;
  const float inv_n = 1.0f / 2048.0f;
  const unsigned short* Qz = Qb + (long)z * 2048 * 128;
  const unsigned short* Kh = Kb + (long)z * 2048 * 128;
  const unsigned short* Vh = Vtb + (long)z * 1024 * 2048 + (long)(vb * 128) * 2048;

  for (int hf = 0; hf < 2; hf++) {
    const int T = hf ? (31 - pair) : pair;
    floatx4 acc[4][2] = {};
    const unsigned short* Qh = Qz + (long)T * 64 * 128;
    bf16x8 aQ[4];
    for (int ke = 0; ke < 4; ke++)
      aQ[ke] = *reinterpret_cast<const bf16x8*>(Qh + (long)(w * 16 + l16) * 128 + ke * 32 + lq * 8);
    for (int M = 0; M <= T; M++) {
      __syncthreads();
      for (int i = 0; i < 4; i++) {
        int lin = i * 256 + t;
        int row = lin >> 4, c8 = lin & 15;
        *reinterpret_cast<uint4*>(&LK[row * 136 + c8 * 8]) =
            *reinterpret_cast<const uint4*>(Kh + (long)(M * 64 + row) * 128 + c8 * 8);
      }
      for (int i = 0; i < 4; i++) {
        int lin = i * 256 + t;
        int row = lin >> 3, c8 = lin & 7;
        *reinterpret_cast<uint4*>(&LV[row * 72 + c8 * 8]) =
            *reinterpret_cast<const uint4*>(Vh + (long)row * 2048 + M * 64 + c8 * 8);
      }
      __syncthreads();
      floatx4 sacc[4] = {};
      for (int ke = 0; ke < 4; ke++)
        for (int mf = 0; mf < 4; mf++) {
          bf16x8 bK = *reinterpret_cast<const bf16x8*>(&LK[(mf * 16 + l16) * 136 + ke * 32 + lq * 8]);
          sacc[mf] = __builtin_amdgcn_mfma_f32_16x16x32_bf16(aQ[ke], bK, sacc[mf], 0, 0, 0);
        }
      __syncthreads();
      const int nloc = w * 16 + lq * 4;
      for (int mf = 0; mf < 4; mf++)
        for (int j = 0; j < 4; j++) {
          float v = fmaxf(sacc[mf][j], 0.0f) * inv_n;
          if (M == T) {
            int mm = mf * 16 + l16;
            if (mm > nloc + j) v = 0.0f;
          }
          LP[(nloc + j) * 72 + mf * 16 + l16] = f2bf(v);
        }
      __syncthreads();
      for (int km = 0; km < 2; km++) {
        bf16x8 aP[4];
        for (int nf = 0; nf < 4; nf++)
          aP[nf] = *reinterpret_cast<const bf16x8*>(&LP[(nf * 16 + l16) * 72 + km * 32 + lq * 8]);
        for (int vf = 0; vf < 2; vf++) {
          bf16x8 bV = *reinterpret_cast<const bf16x8*>(&LV[(w * 32 + vf * 16 + l16) * 72 + km * 32 + lq * 8]);
          for (int nf = 0; nf < 4; nf++)
            acc[nf][vf] = __builtin_amdgcn_mfma_f32_16x16x32_bf16(aP[nf], bV, acc[nf][vf], 0, 0, 0);
        }
      }
    }  // M
    for (int nf = 0; nf < 4; nf++)
      for (int vf = 0; vf < 2; vf++)
        for (int j = 0; j < 4; j++) {
          int n = T * 64 + nf * 16 + lq * 4 + j;
          int v = vb * 128 + w * 32 + vf * 16 + l16;
          long idx = ((long)b * 2048 + n) * 1024 + v;
          unsafeAtomicAdd(&out[idx], acc[nf][vf][j]);
        }
  }  // hf
}

extern "C" void kernel_launch(void* const* d_in, const int* in_sizes, int n_in,
                              void* d_out, int out_size, void* d_ws, size_t ws_size,
                              hipStream_t stream) {
  const float* x  = (const float*)d_in[0];
  const float* Wq = (const float*)d_in[1];
  const float* Wk = (const float*)d_in[2];
  const float* Wv = (const float*)d_in[3];
  float* out = (float*)d_out;
  const size_t MB = 1u << 20;
  dim3 blk(256);

  if (ws_size >= 104 * MB) {
    // layout: Vtb 0..64MB (Wqkb aliases first 4MB, dead before Vt gemm writes)
    unsigned short* Vtb  = (unsigned short*)d_ws;
    unsigned short* Wqkb = (unsigned short*)d_ws;
    unsigned short* Qb   = (unsigned short*)((char*)d_ws + 64 * MB);
    unsigned short* Kb   = (unsigned short*)((char*)d_ws + 72 * MB);
    unsigned short* xb   = (unsigned short*)((char*)d_ws + 80 * MB);
    unsigned short* Wvb  = (unsigned short*)((char*)d_ws + 88 * MB);

    convert_all<<<dim3(2048), blk, 0, stream>>>(
        (const float4*)x, (const float4*)Wq, (const float4*)Wk, (const float4*)Wv,
        (uint2*)xb, (uint2*)Wqkb, (uint2*)Wvb);
    init_out<<<dim3(1024), blk, 0, stream>>>(
        (const float4*)x, (float4*)out, 2 * 2048 * 1024 / 4);
    // Q+K fused: C cols 0..127 -> Qb, 128..255 -> Kb
    gemm_bf16_bt<<<dim3(16, 2, 16), blk, 0, stream>>>(
        xb, (long)2048 * 1024, 0, Wqkb, 0, (long)256 * 1024,
        Qb, (long)2048 * 128, 128, Kb, (long)2048 * 128, 128, 128, 1024);
    // Vt = Wv . x^T  (overwrites Wqkb alias region; Wqkb dead by now)
    gemm_bf16_bt<<<dim3(8, 16, 16), blk, 0, stream>>>(
        Wvb, 0, (long)1024 * 1024, xb, (long)2048 * 1024, 0,
        Vtb, (long)1024 * 2048, 2048, Vtb, 0, 0, 1 << 30, 1024);
    attn_fused<<<dim3(8, 16, 16), blk, 0, stream>>>(Qb, Kb, Vtb, out);
  } else {
    // fallback: R2 path, 80 MB
    unsigned short* Qb  = (unsigned short*)d_ws;
    unsigned short* Kb  = Qb + (size_t)2 * 8 * 2048 * 128;
    unsigned short* Vtb = Kb + (size_t)2 * 8 * 2048 * 128;
    init_out<<<dim3(1024), blk, 0, stream>>>(
        (const float4*)x, (float4*)out, 2 * 2048 * 1024 / 4);
    gemm_qk<<<dim3(16, 2, 16), blk, 0, stream>>>(x, Wq, Wk, Qb, Kb);
    gemm_bt<<<dim3(8, 16, 16), blk, 0, stream>>>(
        Wv, 0, (long)1024 * 1024, x, (long)2048 * 1024, 0,
        Vtb, (long)1024 * 2048, 1024, 2048, 1024, 8);
    attn_fused<<<dim3(8, 16, 16), blk, 0, stream>>>(Qb, Kb, Vtb, out);
  }
}